// Round 10
// baseline (176.221 us; speedup 1.0000x reference)
//
#include <hip/hip_runtime.h>

#define BB 64
#define LL 512
#define SS 512
#define HH 768
#define CC 9
#define NROWS (BB * LL)               // 32768 subword rows
#define RLS 12                        // row-logit stride (floats), 48 B
#define G1 1024                       // row_gemm blocks (32 rows each)
#define WPS 64                        // words per pool block
#define G2 (BB * SS / WPS)            // 512 pool blocks

// DPP full-wave (64-lane) sum; total lands in lane 63. Pure VALU, no LDS.
template <int CTRL>
__device__ __forceinline__ float dpp_add(float x) {
    int y = __builtin_amdgcn_update_dpp(0, __float_as_int(x), CTRL, 0xf, 0xf, true);
    return x + __int_as_float(y);
}
__device__ __forceinline__ float rsum64(float x) {
    x = dpp_add<0x111>(x);  // row_shr:1
    x = dpp_add<0x112>(x);  // row_shr:2
    x = dpp_add<0x114>(x);  // row_shr:4
    x = dpp_add<0x118>(x);  // row_shr:8
    x = dpp_add<0x142>(x);  // row_bcast:15
    x = dpp_add<0x143>(x);  // row_bcast:31 -> lane 63 = full sum
    return x;
}

// Setup: blocks 0..63 = per-batch exclusive scan of ids_lens -> starts;
// blocks 64..77 = W[H][C] -> WT[C][H]; block 0 zeroes the done counter.
__global__ __launch_bounds__(512) void setup_kernel(
    const float* __restrict__ Wm,
    const int* __restrict__ ids_lens,
    int* __restrict__ starts,
    float* __restrict__ WT_g,
    int* __restrict__ done) {
    __shared__ int buf[SS];
    int blk = blockIdx.x, t = threadIdx.x;
    if (blk < BB) {
        int v = ids_lens[blk * SS + t];
        buf[t] = v;
        __syncthreads();
        for (int off = 1; off < SS; off <<= 1) {
            int x = (t >= off) ? buf[t - off] : 0;
            __syncthreads();
            buf[t] += x;
            __syncthreads();
        }
        starts[blk * SS + t] = buf[t] - v;   // exclusive scan
        if (blk == 0 && t == 0) *done = 0;   // ws is re-poisoned every call
    } else {
        int e = (blk - BB) * 512 + t;
        if (e < HH * CC) {
            int h = e / CC;
            int c = e - h * CC;
            WT_g[c * HH + h] = Wm[e];
        }
    }
}

// Row GEMM: per-subword-row logits, rows processed in pairs so >=6 float4
// loads are in flight before any use. No LDS, no barriers.
__global__ __launch_bounds__(256) void row_gemm_kernel(
    const float* __restrict__ bert,   // [B*L, H]
    const float* __restrict__ WT_g,   // [C][H]
    float* __restrict__ RL)           // [NROWS, RLS]
{
    int wave = threadIdx.x >> 6;
    int lane = threadIdx.x & 63;
    int hoff = lane * 4;

    float4 wreg[CC][3];
#pragma unroll
    for (int c = 0; c < CC; c++)
#pragma unroll
        for (int c3 = 0; c3 < 3; c3++)
            wreg[c][c3] = *reinterpret_cast<const float4*>(WT_g + c * HH + c3 * 256 + hoff);

    size_t row0 = (size_t)blockIdx.x * 32 + wave * 8;

#pragma unroll
    for (int rp = 0; rp < 4; ++rp) {
        const float* pa = bert + (row0 + 2 * rp) * HH + hoff;
        const float* pb = pa + HH;
        // 6 loads issued before any dependent use
        float4 a0 = *reinterpret_cast<const float4*>(pa);
        float4 a1 = *reinterpret_cast<const float4*>(pa + 256);
        float4 a2 = *reinterpret_cast<const float4*>(pa + 512);
        float4 b0 = *reinterpret_cast<const float4*>(pb);
        float4 b1 = *reinterpret_cast<const float4*>(pb + 256);
        float4 b2 = *reinterpret_cast<const float4*>(pb + 512);

        float acca[CC], accb[CC];
#pragma unroll
        for (int c = 0; c < CC; c++) {
            acca[c] = a0.x * wreg[c][0].x + a0.y * wreg[c][0].y
                    + a0.z * wreg[c][0].z + a0.w * wreg[c][0].w
                    + a1.x * wreg[c][1].x + a1.y * wreg[c][1].y
                    + a1.z * wreg[c][1].z + a1.w * wreg[c][1].w
                    + a2.x * wreg[c][2].x + a2.y * wreg[c][2].y
                    + a2.z * wreg[c][2].z + a2.w * wreg[c][2].w;
            accb[c] = b0.x * wreg[c][0].x + b0.y * wreg[c][0].y
                    + b0.z * wreg[c][0].z + b0.w * wreg[c][0].w
                    + b1.x * wreg[c][1].x + b1.y * wreg[c][1].y
                    + b1.z * wreg[c][1].z + b1.w * wreg[c][1].w
                    + b2.x * wreg[c][2].x + b2.y * wreg[c][2].y
                    + b2.z * wreg[c][2].z + b2.w * wreg[c][2].w;
        }
#pragma unroll
        for (int c = 0; c < CC; c++) { acca[c] = rsum64(acca[c]); accb[c] = rsum64(accb[c]); }

        if (lane == 63) {
            float* da = RL + (row0 + 2 * rp) * RLS;
            float* db = da + RLS;
            float4 s0, s1;
            s0.x = acca[0]; s0.y = acca[1]; s0.z = acca[2]; s0.w = acca[3];
            s1.x = acca[4]; s1.y = acca[5]; s1.z = acca[6]; s1.w = acca[7];
            *reinterpret_cast<float4*>(da) = s0;
            *reinterpret_cast<float4*>(da + 4) = s1;
            da[8] = acca[8];
            s0.x = accb[0]; s0.y = accb[1]; s0.z = accb[2]; s0.w = accb[3];
            s1.x = accb[4]; s1.y = accb[5]; s1.z = accb[6]; s1.w = accb[7];
            *reinterpret_cast<float4*>(db) = s0;
            *reinterpret_cast<float4*>(db + 4) = s1;
            db[8] = accb[8];
        }
    }
}

// Pool + softmax/NLL/argmax + done-counter finalize. 64 threads = 64 words.
__global__ __launch_bounds__(64) void pool_kernel(
    const float* __restrict__ RL,       // [NROWS, RLS]
    const float* __restrict__ bias,     // [C]
    const int* __restrict__ ids_lens,   // [B, S]
    const int* __restrict__ label_ids,  // [B, S]
    const int* __restrict__ starts,     // [B, S]
    float* __restrict__ pred_out,       // d_out + 1
    float* __restrict__ nll_part,       // [G2]
    float* __restrict__ cnt_part,       // [G2]
    int* __restrict__ done,
    float* __restrict__ out_loss)       // d_out
{
    __shared__ int s_old;
    int b = blockIdx.x >> 3;
    int s8 = blockIdx.x & 7;
    int k = threadIdx.x;                // 0..63, one word per lane
    int g = b * SS + s8 * WPS + k;

    int len = ids_lens[g];
    int off = starts[g];
    const float* base = RL + ((size_t)b * LL + off) * RLS;

    float s[CC];
#pragma unroll
    for (int c = 0; c < CC; c++) s[c] = 0.0f;
    for (int j = 0; j < len; ++j) {
        const float* p = base + j * RLS;
        float4 a = *reinterpret_cast<const float4*>(p);
        float4 c4 = *reinterpret_cast<const float4*>(p + 4);
        s[0] += a.x;  s[1] += a.y;  s[2] += a.z;  s[3] += a.w;
        s[4] += c4.x; s[5] += c4.y; s[6] += c4.z; s[7] += c4.w;
        s[8] += p[8];
    }
    float inv = 1.0f / (float)(len > 0 ? len : 1);
    float lg[CC];
#pragma unroll
    for (int c = 0; c < CC; c++) lg[c] = s[c] * inv + bias[c];

    float mx = lg[0];
    int arg = 0;
#pragma unroll
    for (int c = 1; c < CC; c++) {
        if (lg[c] > mx) { mx = lg[c]; arg = c; }
    }
    float se = 0.0f;
#pragma unroll
    for (int c = 0; c < CC; c++) se += expf(lg[c] - mx);
    float lse = mx + logf(se);

    int lab = label_ids[g];
    lab = lab < 0 ? 0 : (lab > CC - 1 ? CC - 1 : lab);
    float valid = (len > 0) ? 1.0f : 0.0f;
    float nll = (lse - lg[lab]) * valid;

    pred_out[g] = (float)arg;

    float rn = rsum64(nll);
    float rc = rsum64(valid);
    if (k == 63) {
        nll_part[blockIdx.x] = rn;
        cnt_part[blockIdx.x] = rc;
    }
    __threadfence();                    // k63's partial visible device-wide
    __syncthreads();                    // order k63's fence before k0's atomic
    if (k == 0) s_old = atomicAdd(done, 1);
    __syncthreads();

    if (s_old == G2 - 1) {              // last block finalizes
        __threadfence();                // acquire all partials
        float n = 0.0f, c = 0.0f;
#pragma unroll
        for (int i = 0; i < G2 / 64; i++) {
            n += nll_part[k + 64 * i];
            c += cnt_part[k + 64 * i];
        }
        n = rsum64(n);
        c = rsum64(c);
        if (k == 63) out_loss[0] = n / fmaxf(c, 1.0f);
    }
}

extern "C" void kernel_launch(void* const* d_in, const int* in_sizes, int n_in,
                              void* d_out, int out_size, void* d_ws, size_t ws_size,
                              hipStream_t stream) {
    const float* bert = (const float*)d_in[0]; // float32 [B,L,H]
    const float* Wm   = (const float*)d_in[1]; // float32 [H,C]
    const float* bias = (const float*)d_in[2]; // float32 [C]
    // d_in[3] = attention_mask (unused: prefix mask implied by ids_lens)
    const int* ids_lens  = (const int*)d_in[4];
    const int* label_ids = (const int*)d_in[5];
    // d_in[6] = label_mask (derived from ids_lens > 0)

    float* out = (float*)d_out;  // [0]=loss, [1..32768]=pred, float32

    float* WT_g     = (float*)d_ws;                    // [C][H]   27648 B (16B-aligned)
    float* RL       = WT_g + CC * HH;                  // [NROWS][RLS] 1.57 MB
    float* nll_part = RL + (size_t)NROWS * RLS;        // [G2]
    float* cnt_part = nll_part + G2;                   // [G2]
    int*   starts   = (int*)(cnt_part + G2);           // [B*S]
    int*   done     = starts + BB * SS;                // [1]

    setup_kernel<<<BB + (HH * CC + 511) / 512, 512, 0, stream>>>(Wm, ids_lens,
                                                                 starts, WT_g, done);
    row_gemm_kernel<<<G1, 256, 0, stream>>>(bert, WT_g, RL);
    pool_kernel<<<G2, 64, 0, stream>>>(RL, bias, ids_lens, label_ids, starts,
                                       out + 1, nll_part, cnt_part, done, out);
}

// Round 11
// 169.508 us; speedup vs baseline: 1.0396x; 1.0396x over previous
//
#include <hip/hip_runtime.h>

#define BB 64
#define LL 512
#define SS 512
#define HH 768
#define CC 9
#define NROWS (BB * LL)               // 32768 subword rows
#define RLS 12                        // row-logit stride (floats)
#define RPB 16                        // rows per row_gemm block
#define G1 (NROWS / RPB)              // 2048 blocks x 192 threads (3 waves)
#define WPS 64                        // words per pool slice
#define G2 (BB * SS / WPS)            // 512 pool blocks

// DPP full-wave (64-lane) sum; total lands in lane 63. Pure VALU, no LDS.
template <int CTRL>
__device__ __forceinline__ float dpp_add(float x) {
    int y = __builtin_amdgcn_update_dpp(0, __float_as_int(x), CTRL, 0xf, 0xf, true);
    return x + __int_as_float(y);
}
__device__ __forceinline__ float rsum64(float x) {
    x = dpp_add<0x111>(x);  // row_shr:1
    x = dpp_add<0x112>(x);  // row_shr:2
    x = dpp_add<0x114>(x);  // row_shr:4
    x = dpp_add<0x118>(x);  // row_shr:8
    x = dpp_add<0x142>(x);  // row_bcast:15
    x = dpp_add<0x143>(x);  // row_bcast:31 -> lane 63 = full sum
    return x;
}

// Kernel 0: W[H][C] -> WT[C][H] in ws (27 KB, L2-resident after)
__global__ __launch_bounds__(256) void wt_kernel(const float* __restrict__ Wm,
                                                 float* __restrict__ WT_g) {
    int e = blockIdx.x * 256 + threadIdx.x;   // coalesced read of Wm
    if (e < HH * CC) {
        int h = e / CC;
        int c = e - h * CC;
        WT_g[c * HH + h] = Wm[e];
    }
}

// Kernel 1: streaming per-subword-row logits.
// 3 waves/block; wave w owns classes 3w..3w+2 -> W slice is only 36 floats
// per lane (guaranteed register-resident). All 3 waves stream the same 16
// rows; waves 2,3 hit L1/L2 so HBM traffic stays 1x. Barrier bounds skew.
__global__ __launch_bounds__(192) void row_gemm_kernel(
    const float* __restrict__ bert,   // [B*L, H]
    const float* __restrict__ WT_g,   // [C][H]
    float* __restrict__ RL)           // [NROWS, RLS]
{
    int wave = threadIdx.x >> 6;      // 0..2 -> class group
    int lane = threadIdx.x & 63;
    int hoff = lane * 4;
    int c0 = wave * 3;

    // 3 classes x 3 float4 = 36 floats of W per lane: stays in VGPRs.
    float4 wreg[3][3];
#pragma unroll
    for (int c = 0; c < 3; c++)
#pragma unroll
        for (int c3 = 0; c3 < 3; c3++)
            wreg[c][c3] = *reinterpret_cast<const float4*>(
                WT_g + (c0 + c) * HH + c3 * 256 + hoff);

    size_t row0 = (size_t)blockIdx.x * RPB;

#pragma unroll
    for (int r = 0; r < RPB; ++r) {
        if (r == RPB / 2) __syncthreads();   // keep waves' row windows in L1
        const float* p = bert + (row0 + r) * HH + hoff;
        float4 f0 = *reinterpret_cast<const float4*>(p);
        float4 f1 = *reinterpret_cast<const float4*>(p + 256);
        float4 f2 = *reinterpret_cast<const float4*>(p + 512);

        float acc[3];
#pragma unroll
        for (int c = 0; c < 3; c++) {
            acc[c] = f0.x * wreg[c][0].x + f0.y * wreg[c][0].y
                   + f0.z * wreg[c][0].z + f0.w * wreg[c][0].w
                   + f1.x * wreg[c][1].x + f1.y * wreg[c][1].y
                   + f1.z * wreg[c][1].z + f1.w * wreg[c][1].w
                   + f2.x * wreg[c][2].x + f2.y * wreg[c][2].y
                   + f2.z * wreg[c][2].z + f2.w * wreg[c][2].w;
        }
#pragma unroll
        for (int c = 0; c < 3; c++) acc[c] = rsum64(acc[c]);

        if (lane == 63) {
            float* dst = RL + (row0 + r) * RLS + c0;
            dst[0] = acc[0];
            dst[1] = acc[1];
            dst[2] = acc[2];
        }
    }
}

// Kernel 2: 512 blocks, each owns 64 words of one batch: slice offset +
// mini-scan + pool + softmax/NLL/argmax + per-block partial (no atomics).
__global__ __launch_bounds__(256) void pool_kernel(
    const float* __restrict__ RL,       // [NROWS, RLS]
    const float* __restrict__ bias,     // [C]
    const int* __restrict__ ids_lens,   // [B, S]
    const int* __restrict__ label_ids,  // [B, S]
    float* __restrict__ pred_out,       // d_out + 1
    float* __restrict__ nll_part,       // [G2]
    float* __restrict__ cnt_part)       // [G2]
{
    __shared__ int wlen[WPS], woff[WPS];
    __shared__ float red[4];
    __shared__ int s_start;

    int b = blockIdx.x >> 3;            // batch
    int s8 = blockIdx.x & 7;            // slice in batch
    int w0 = s8 * WPS;                  // first word of slice
    const int* lens = ids_lens + b * SS;

    int t = threadIdx.x, lane = t & 63, wave = t >> 6;

    if (t < WPS) wlen[t] = lens[w0 + t];

    // sum of lens[0..w0) -> slice's first subword row
    int part = 0;
    for (int i = t; i < w0; i += 256) part += lens[i];
    float pf = rsum64((float)part);     // integers < 1536: exact
    if (lane == 63) red[wave] = pf;
    __syncthreads();
    if (t == 0) {
        int run = 0;
#pragma unroll
        for (int k = 0; k < WPS; k++) { woff[k] = run; run += wlen[k]; }
        s_start = (int)(red[0] + red[1] + red[2] + red[3]);
    }
    __syncthreads();

    if (t < 64) {
        int k = t;
        int len = wlen[k];
        int off = s_start + woff[k];
        const float* base = RL + ((size_t)b * LL + off) * RLS;

        float s[CC];
#pragma unroll
        for (int c = 0; c < CC; c++) s[c] = 0.0f;
        for (int j = 0; j < len; ++j) {
            const float* p = base + j * RLS;
            float4 a = *reinterpret_cast<const float4*>(p);
            float4 c4 = *reinterpret_cast<const float4*>(p + 4);
            s[0] += a.x;  s[1] += a.y;  s[2] += a.z;  s[3] += a.w;
            s[4] += c4.x; s[5] += c4.y; s[6] += c4.z; s[7] += c4.w;
            s[8] += p[8];
        }
        float inv = 1.0f / (float)(len > 0 ? len : 1);
        float lg[CC];
#pragma unroll
        for (int c = 0; c < CC; c++) lg[c] = s[c] * inv + bias[c];

        float mx = lg[0];
        int arg = 0;
#pragma unroll
        for (int c = 1; c < CC; c++) {
            if (lg[c] > mx) { mx = lg[c]; arg = c; }
        }
        float se = 0.0f;
#pragma unroll
        for (int c = 0; c < CC; c++) se += expf(lg[c] - mx);
        float lse = mx + logf(se);

        int g = b * SS + w0 + k;
        int lab = label_ids[g];
        lab = lab < 0 ? 0 : (lab > CC - 1 ? CC - 1 : lab);
        float valid = (len > 0) ? 1.0f : 0.0f;
        float nll = (lse - lg[lab]) * valid;

        pred_out[g] = (float)arg;

        float rn = rsum64(nll);
        float rc = rsum64(valid);
        if (t == 63) {
            nll_part[blockIdx.x] = rn;
            cnt_part[blockIdx.x] = rc;
        }
    }
}

// Kernel 3: deterministic reduction of 512 block partials -> loss
__global__ __launch_bounds__(512) void finalize_kernel(
    const float* __restrict__ nll_part,
    const float* __restrict__ cnt_part,
    float* __restrict__ out_loss) {
    __shared__ float sn[8], sc[8];
    int t = threadIdx.x, lane = t & 63, wave = t >> 6;
    float n = rsum64(nll_part[t]);
    float c = rsum64(cnt_part[t]);
    if (lane == 63) { sn[wave] = n; sc[wave] = c; }
    __syncthreads();
    if (t == 0) {
        float tn = 0.0f, tc = 0.0f;
#pragma unroll
        for (int i = 0; i < 8; i++) { tn += sn[i]; tc += sc[i]; }
        out_loss[0] = tn / fmaxf(tc, 1.0f);
    }
}

extern "C" void kernel_launch(void* const* d_in, const int* in_sizes, int n_in,
                              void* d_out, int out_size, void* d_ws, size_t ws_size,
                              hipStream_t stream) {
    const float* bert = (const float*)d_in[0]; // float32 [B,L,H]
    const float* Wm   = (const float*)d_in[1]; // float32 [H,C]
    const float* bias = (const float*)d_in[2]; // float32 [C]
    // d_in[3] = attention_mask (unused: prefix mask implied by ids_lens)
    const int* ids_lens  = (const int*)d_in[4];
    const int* label_ids = (const int*)d_in[5];
    // d_in[6] = label_mask (derived from ids_lens > 0)

    float* out = (float*)d_out;  // [0]=loss, [1..32768]=pred, float32

    float* WT_g     = (float*)d_ws;                    // [C][H]  27648 B
    float* RL       = WT_g + CC * HH;                  // [NROWS][RLS] 1.57 MB
    float* nll_part = RL + (size_t)NROWS * RLS;        // [G2]
    float* cnt_part = nll_part + G2;                   // [G2]

    wt_kernel<<<(HH * CC + 255) / 256, 256, 0, stream>>>(Wm, WT_g);
    row_gemm_kernel<<<G1, 192, 0, stream>>>(bert, WT_g, RL);
    pool_kernel<<<G2, 256, 0, stream>>>(RL, bias, ids_lens, label_ids,
                                        out + 1, nll_part, cnt_part);
    finalize_kernel<<<1, 512, 0, stream>>>(nll_part, cnt_part, out);
}